// Round 4
// baseline (139.710 us; speedup 1.0000x reference)
//
#include <hip/hip_runtime.h>
#include <math.h>

#define CT    320
#define NPTS  1024
#define DFEAT 256
#define DPOS  64
#define KSEL  32

// ================= Kernel A: sim + exact top-32 + softmax -> pairs(ws) ======
// 1024 blocks x 256 threads; 16 rows/block; all 4 blocks/CU co-resident.
// Per wave: register-local partial top-32 over its 256-j range (no sim LDS
// roundtrip), then a 128->32 merge per row. Exact: global top-32 is a subset
// of the union of per-range top-32s; (v desc, j asc) ordering everywhere.
#define AROWS 16
__global__ __launch_bounds__(256, 4) void gnn_sim_topk(const float* __restrict__ in,
                                                       float2* __restrict__ pairs) {
  __shared__ float pi[DPOS * 20];      // [d][i], stride 20 (16B-aligned quads)
  __shared__ float rni[AROWS];
  __shared__ float cand[AROWS][260];   // 128 interleaved (v,j) pairs + pad

  const int p     = blockIdx.x;
  const int batch = ((p & 7) << 1) | ((p >> 3) & 1);   // 2 batches per XCD
  const int chunk = p >> 4;            // 0..63
  const int i0    = chunk * AROWS;
  const int tid   = threadIdx.x;
  const int w     = tid >> 6;
  const int lane  = tid & 63;

  const float* __restrict__ fbase = in + (size_t)batch * CT * NPTS;
  const float* __restrict__ pbase = fbase + (size_t)DFEAT * NPTS;

  // stage raw pos of the 16 rows
  {
    const int i = tid & 15;
    const int d0 = tid >> 4;           // 0..15
#pragma unroll
    for (int pass = 0; pass < 4; ++pass) {
      const int d = pass * 16 + d0;
      pi[d * 20 + i] = pbase[(size_t)d * NPTS + i0 + i];
    }
  }
  __syncthreads();
  if (tid < AROWS) {
    float s = 0.f;
#pragma unroll
    for (int d = 0; d < DPOS; ++d) { const float x = pi[d * 20 + tid]; s = fmaf(x, x, s); }
    rni[tid] = 1.0f / fmaxf(sqrtf(s), 1e-12f);
  }
  __syncthreads();

  // sim outer-product: wave w owns j in [w*256, (w+1)*256), lane owns 4 j
  float acc[AROWS][4];
#pragma unroll
  for (int r = 0; r < AROWS; ++r) { acc[r][0]=0.f; acc[r][1]=0.f; acc[r][2]=0.f; acc[r][3]=0.f; }
  float ssq0=0.f, ssq1=0.f, ssq2=0.f, ssq3=0.f;
  const float* jp = pbase + w * 256 + lane * 4;
#pragma unroll 4
  for (int d = 0; d < DPOS; ++d) {
    const float4 jv = *(const float4*)(jp + (size_t)d * NPTS);
    ssq0 = fmaf(jv.x, jv.x, ssq0);
    ssq1 = fmaf(jv.y, jv.y, ssq1);
    ssq2 = fmaf(jv.z, jv.z, ssq2);
    ssq3 = fmaf(jv.w, jv.w, ssq3);
#pragma unroll
    for (int rr = 0; rr < 4; ++rr) {
      const float4 p4 = *(const float4*)&pi[d * 20 + rr * 4];   // broadcast
      const float pv[4] = {p4.x, p4.y, p4.z, p4.w};
#pragma unroll
      for (int u = 0; u < 4; ++u) {
        acc[rr*4+u][0] = fmaf(pv[u], jv.x, acc[rr*4+u][0]);
        acc[rr*4+u][1] = fmaf(pv[u], jv.y, acc[rr*4+u][1]);
        acc[rr*4+u][2] = fmaf(pv[u], jv.z, acc[rr*4+u][2]);
        acc[rr*4+u][3] = fmaf(pv[u], jv.w, acc[rr*4+u][3]);
      }
    }
  }
  const float rnj0 = 1.0f / fmaxf(sqrtf(ssq0), 1e-12f);
  const float rnj1 = 1.0f / fmaxf(sqrtf(ssq1), 1e-12f);
  const float rnj2 = 1.0f / fmaxf(sqrtf(ssq2), 1e-12f);
  const float rnj3 = 1.0f / fmaxf(sqrtf(ssq3), 1e-12f);

  // ---- per-wave partial top-32 over its 256-j range, straight from regs ----
  const int jbase = w * 256 + lane * 4;
  for (int r = 0; r < AROWS; ++r) {
    const float sc = rni[r];
    float v[4];
    v[0] = acc[r][0] * rnj0 * sc;
    v[1] = acc[r][1] * rnj1 * sc;
    v[2] = acc[r][2] * rnj2 * sc;
    v[3] = acc[r][3] * rnj3 * sc;
    int q[4];
#pragma unroll
    for (int t = 0; t < 4; ++t) {
      float f = (v[t] + 1.0f) * 512.0f;
      f = fminf(fmaxf(f, 0.0f), 1023.0f);
      q[t] = (int)f;
    }
    // largest lo with count(q >= lo) >= 32 within this 256-j range
    int lo = 0;
#pragma unroll
    for (int bit = 512; bit >= 1; bit >>= 1) {
      const int mid = lo + bit;
      int cnt = 0;
#pragma unroll
      for (int t = 0; t < 4; ++t) cnt += (int)__popcll(__ballot(q[t] >= mid));
      if (cnt >= KSEL) lo = mid;
    }
    int cbase = 0;
    unsigned cmask = 0u;
    const int thr = lo + 1;
    float* const crow = &cand[r][2 * (w * KSEL)];   // this wave's 32-pair slot
#pragma unroll
    for (int t = 0; t < 4; ++t) {
      const bool hi = (q[t] >= thr);
      const unsigned long long m = __ballot(hi);
      if (hi) {
        const int pos = cbase + (int)__builtin_amdgcn_mbcnt_hi(
            (unsigned)(m >> 32), __builtin_amdgcn_mbcnt_lo((unsigned)m, 0u));
        crow[2 * pos]     = v[t];
        crow[2 * pos + 1] = __int_as_float(jbase + t);
      }
      cbase += (int)__popcll(m);
      if (q[t] == lo) cmask |= (1u << t);
    }
    const int need = KSEL - cbase;
    for (int it = 0; it < need; ++it) {
      float bv = -2.0f; int bj = 0x7fffffff; int bt = 4;
#pragma unroll
      for (int t = 0; t < 4; ++t) {
        if (((cmask >> t) & 1u) && v[t] > bv) { bv = v[t]; bj = jbase + t; bt = t; }
      }
      float rv = bv; int rj = bj;
#pragma unroll
      for (int s = 1; s < 64; s <<= 1) {
        const float ov = __shfl_xor(rv, s);
        const int   oj = __shfl_xor(rj, s);
        if (ov > rv || (ov == rv && oj < rj)) { rv = ov; rj = oj; }
      }
      if (bv == rv && bj == rj) {          // unique winner (j unique)
        crow[2 * (cbase + it)]     = bv;
        crow[2 * (cbase + it) + 1] = __int_as_float(bj);
        cmask &= ~(1u << bt);
      }
    }
  }
  __syncthreads();

  // ---- merge 128 candidates -> exact top-32, softmax; wave w owns 4 rows ----
#pragma unroll
  for (int rr = 0; rr < 4; ++rr) {
    const int r = w * 4 + rr;
    const float4 c4 = *(const float4*)&cand[r][lane * 4];   // 2 pairs per lane
    float v2[2] = { c4.x, c4.z };
    int   j2[2] = { __float_as_int(c4.y), __float_as_int(c4.w) };
    int q2[2];
#pragma unroll
    for (int t = 0; t < 2; ++t) {
      float f = (v2[t] + 1.0f) * 512.0f;
      f = fminf(fmaxf(f, 0.0f), 1023.0f);
      q2[t] = (int)f;
    }
    int lo = 0;
#pragma unroll
    for (int bit = 512; bit >= 1; bit >>= 1) {
      const int mid = lo + bit;
      int cnt = (int)__popcll(__ballot(q2[0] >= mid)) + (int)__popcll(__ballot(q2[1] >= mid));
      if (cnt >= KSEL) lo = mid;
    }
    int cbase = 0;
    unsigned cmask = 0u;
    const int thr = lo + 1;
#pragma unroll
    for (int t = 0; t < 2; ++t) {
      const bool hi = (q2[t] >= thr);
      const unsigned long long m = __ballot(hi);
      if (hi) {
        const int pos = cbase + (int)__builtin_amdgcn_mbcnt_hi(
            (unsigned)(m >> 32), __builtin_amdgcn_mbcnt_lo((unsigned)m, 0u));
        cand[r][2 * pos]     = v2[t];
        cand[r][2 * pos + 1] = __int_as_float(j2[t]);
      }
      cbase += (int)__popcll(m);
      if (q2[t] == lo) cmask |= (1u << t);
    }
    const int need = KSEL - cbase;
    for (int it = 0; it < need; ++it) {
      float bv = -2.0f; int bj = 0x7fffffff; int bt = 2;
#pragma unroll
      for (int t = 0; t < 2; ++t) {
        if (((cmask >> t) & 1u) && v2[t] > bv) { bv = v2[t]; bj = j2[t]; bt = t; }
      }
      float rv = bv; int rj = bj;
#pragma unroll
      for (int s = 1; s < 64; s <<= 1) {
        const float ov = __shfl_xor(rv, s);
        const int   oj = __shfl_xor(rj, s);
        if (ov > rv || (ov == rv && oj < rj)) { rv = ov; rj = oj; }
      }
      if (bv == rv && bj == rj) {
        cand[r][2 * (cbase + it)]     = bv;
        cand[r][2 * (cbase + it) + 1] = __int_as_float(bj);
        cmask &= ~(1u << bt);
      }
    }
    // softmax over the selected 32 (order-invariant); halves duplicate work
    {
      const float x = cand[r][2 * (lane & 31)];
      float mx = x;
#pragma unroll
      for (int s = 16; s >= 1; s >>= 1) mx = fmaxf(mx, __shfl_xor(mx, s));
      const float e = expf(x - mx);
      float sum = e;
#pragma unroll
      for (int s = 16; s >= 1; s >>= 1) sum += __shfl_xor(sum, s);
      if (lane < KSEL) cand[r][2 * lane] = e / sum;
    }
  }
  __syncthreads();

  // write (attn, id) pairs, coalesced float4 (2 pairs per thread)
  {
    const int pidx = tid * 2;            // pair index
    const int r = pidx >> 5, k = pidx & 31;
    const float4 o4 = *(const float4*)&cand[r][2 * k];
    *(float4*)&pairs[((size_t)batch * NPTS + i0 + r) * KSEL + k] = o4;
  }
}

// ================= Kernel B: gather (broadcast-j, conflict-light) ===========
// 512 blocks x 256 threads; 32 rows/block; double-buffered global_load_lds.
__global__ __launch_bounds__(256, 2) void gnn_gather(const float* __restrict__ in,
                                                     const float2* __restrict__ pairs,
                                                     float* __restrict__ out) {
  __shared__ float fst[2][8 * 1028];   // 8 channel-rows per cc pass
  __shared__ float pr[32 * 68];        // [row][34 pairs]: a at 2k, j-bits at 2k+1

  const int p     = blockIdx.x;
  const int batch = ((p & 7) << 1) | ((p >> 3) & 1);
  const int chunk = p >> 4;            // 0..31
  const int i0    = chunk * 32;
  const int tid   = threadIdx.x;
  const int w     = tid >> 6;
  const int lane  = tid & 63;

  const float* __restrict__ fbase = in + (size_t)batch * CT * NPTS;

  // pairs -> LDS (1024 pairs = 512 float4)
  {
    const float4* pb4 = (const float4*)(pairs + ((size_t)batch * NPTS + i0) * KSEL);
#pragma unroll
    for (int h = 0; h < 2; ++h) {
      const int pidx = h * 256 + tid;          // float4 index: 2 pairs each
      const float4 q4 = pb4[pidx];
      const int r = pidx >> 4;                 // 16 float4 per row
      const int u = pidx & 15;
      *(float4*)&pr[r * 68 + u * 4] = q4;
    }
  }

  // stage helper: wave w stages channel-rows {2w, 2w+1} of pass cc into buf
#define STAGE(buf, ccv)                                                          \
  do {                                                                           \
    _Pragma("unroll")                                                            \
    for (int rr = 0; rr < 2; ++rr) {                                             \
      const int crow = w * 2 + rr;                                               \
      const float* src = fbase + (size_t)((ccv) * 8 + crow) * NPTS + lane * 4;   \
      float* dst = &fst[buf][crow * 1028];                                       \
      _Pragma("unroll")                                                          \
      for (int qq = 0; qq < 4; ++qq)                                             \
        __builtin_amdgcn_global_load_lds(                                        \
            (const __attribute__((address_space(1))) void*)(src + qq * 256),     \
            (__attribute__((address_space(3))) void*)(dst + qq * 256), 16, 0, 0);\
    }                                                                            \
  } while (0)

  STAGE(0, 0);
  asm volatile("s_waitcnt vmcnt(0)" ::: "memory");
  __syncthreads();

  const int c   = lane >> 3;           // channel slot 0..7
  const int rl  = lane & 7;
  const int row = w * 8 + rl;          // output row 0..31
  const float* prr = &pr[row * 68];

  for (int cc = 0; cc < 32; ++cc) {
    const int cur = cc & 1;
    if (cc < 31) STAGE(cur ^ 1, cc + 1);

    const float* fb = &fst[cur][c * 1028];
    float o = 0.f;
#pragma unroll
    for (int k = 0; k < KSEL; ++k) {
      const float2 pj = *(const float2*)&prr[2 * k];   // conflict-free broadcast
      o = fmaf(pj.x, fb[__float_as_int(pj.y)], o);     // 8 random j per instr
    }
    out[((size_t)batch * DFEAT + cc * 8 + c) * NPTS + i0 + row] = o;

    asm volatile("s_waitcnt vmcnt(0)" ::: "memory");
    __syncthreads();
  }
#undef STAGE
}

extern "C" void kernel_launch(void* const* d_in, const int* in_sizes, int n_in,
                              void* d_out, int out_size, void* d_ws, size_t ws_size,
                              hipStream_t stream) {
  const float* in = (const float*)d_in[0];
  float* out = (float*)d_out;
  float2* pairs = (float2*)d_ws;       // 16*1024*32*8B = 4 MB
  gnn_sim_topk<<<dim3(1024), dim3(256), 0, stream>>>(in, pairs);
  gnn_gather<<<dim3(512), dim3(256), 0, stream>>>(in, pairs, out);
}

// Round 5
// 131.272 us; speedup vs baseline: 1.0643x; 1.0643x over previous
//
#include <hip/hip_runtime.h>
#include <math.h>

#define CT    320
#define NPTS  1024
#define DFEAT 256
#define DPOS  64
#define KSEL  32

// ================= Kernel A: sim + exact top-32 + softmax -> pairs(ws) ======
// 1024 blocks x 256 threads; 16 rows/block; all 4 blocks/CU co-resident.
// Per wave: register-local partial top-32 over its 256-j range (no sim LDS
// roundtrip), then a 128->32 merge per row. Exact: global top-32 is a subset
// of the union of per-range top-32s; (v desc, j asc) ordering everywhere.
#define AROWS 16
__global__ __launch_bounds__(256, 4) void gnn_sim_topk(const float* __restrict__ in,
                                                       float2* __restrict__ pairs) {
  __shared__ float pi[DPOS * 20];      // [d][i], stride 20 (16B-aligned quads)
  __shared__ float rni[AROWS];
  __shared__ float cand[AROWS][260];   // 128 interleaved (v,j) pairs + pad

  const int p     = blockIdx.x;
  const int batch = ((p & 7) << 1) | ((p >> 3) & 1);   // 2 batches per XCD
  const int chunk = p >> 4;            // 0..63
  const int i0    = chunk * AROWS;
  const int tid   = threadIdx.x;
  const int w     = tid >> 6;
  const int lane  = tid & 63;

  const float* __restrict__ fbase = in + (size_t)batch * CT * NPTS;
  const float* __restrict__ pbase = fbase + (size_t)DFEAT * NPTS;

  // stage raw pos of the 16 rows
  {
    const int i = tid & 15;
    const int d0 = tid >> 4;           // 0..15
#pragma unroll
    for (int pass = 0; pass < 4; ++pass) {
      const int d = pass * 16 + d0;
      pi[d * 20 + i] = pbase[(size_t)d * NPTS + i0 + i];
    }
  }
  __syncthreads();
  if (tid < AROWS) {
    float s = 0.f;
#pragma unroll
    for (int d = 0; d < DPOS; ++d) { const float x = pi[d * 20 + tid]; s = fmaf(x, x, s); }
    rni[tid] = 1.0f / fmaxf(sqrtf(s), 1e-12f);
  }
  __syncthreads();

  // sim outer-product: wave w owns j in [w*256, (w+1)*256), lane owns 4 j
  float acc[AROWS][4];
#pragma unroll
  for (int r = 0; r < AROWS; ++r) { acc[r][0]=0.f; acc[r][1]=0.f; acc[r][2]=0.f; acc[r][3]=0.f; }
  float ssq0=0.f, ssq1=0.f, ssq2=0.f, ssq3=0.f;
  const float* jp = pbase + w * 256 + lane * 4;
#pragma unroll 4
  for (int d = 0; d < DPOS; ++d) {
    const float4 jv = *(const float4*)(jp + (size_t)d * NPTS);
    ssq0 = fmaf(jv.x, jv.x, ssq0);
    ssq1 = fmaf(jv.y, jv.y, ssq1);
    ssq2 = fmaf(jv.z, jv.z, ssq2);
    ssq3 = fmaf(jv.w, jv.w, ssq3);
#pragma unroll
    for (int rr = 0; rr < 4; ++rr) {
      const float4 p4 = *(const float4*)&pi[d * 20 + rr * 4];   // broadcast
      const float pv[4] = {p4.x, p4.y, p4.z, p4.w};
#pragma unroll
      for (int u = 0; u < 4; ++u) {
        acc[rr*4+u][0] = fmaf(pv[u], jv.x, acc[rr*4+u][0]);
        acc[rr*4+u][1] = fmaf(pv[u], jv.y, acc[rr*4+u][1]);
        acc[rr*4+u][2] = fmaf(pv[u], jv.z, acc[rr*4+u][2]);
        acc[rr*4+u][3] = fmaf(pv[u], jv.w, acc[rr*4+u][3]);
      }
    }
  }
  const float rnj0 = 1.0f / fmaxf(sqrtf(ssq0), 1e-12f);
  const float rnj1 = 1.0f / fmaxf(sqrtf(ssq1), 1e-12f);
  const float rnj2 = 1.0f / fmaxf(sqrtf(ssq2), 1e-12f);
  const float rnj3 = 1.0f / fmaxf(sqrtf(ssq3), 1e-12f);

  // ---- per-wave partial top-32 over its 256-j range, straight from regs ----
  // FULLY UNROLLED: acc[] must be statically indexed or it spills to scratch
  // (round-4 regression: 126 MB scratch writes, VGPR 60, +16 us).
  const int jbase = w * 256 + lane * 4;
#pragma unroll
  for (int r = 0; r < AROWS; ++r) {
    const float sc = rni[r];
    float v[4];
    v[0] = acc[r][0] * rnj0 * sc;
    v[1] = acc[r][1] * rnj1 * sc;
    v[2] = acc[r][2] * rnj2 * sc;
    v[3] = acc[r][3] * rnj3 * sc;
    int q[4];
#pragma unroll
    for (int t = 0; t < 4; ++t) {
      float f = (v[t] + 1.0f) * 512.0f;
      f = fminf(fmaxf(f, 0.0f), 1023.0f);
      q[t] = (int)f;
    }
    // largest lo with count(q >= lo) >= 32 within this 256-j range
    int lo = 0;
#pragma unroll
    for (int bit = 512; bit >= 1; bit >>= 1) {
      const int mid = lo + bit;
      int cnt = 0;
#pragma unroll
      for (int t = 0; t < 4; ++t) cnt += (int)__popcll(__ballot(q[t] >= mid));
      if (cnt >= KSEL) lo = mid;
    }
    int cbase = 0;
    unsigned cmask = 0u;
    const int thr = lo + 1;
    float* const crow = &cand[r][2 * (w * KSEL)];   // this wave's 32-pair slot
#pragma unroll
    for (int t = 0; t < 4; ++t) {
      const bool hi = (q[t] >= thr);
      const unsigned long long m = __ballot(hi);
      if (hi) {
        const int pos = cbase + (int)__builtin_amdgcn_mbcnt_hi(
            (unsigned)(m >> 32), __builtin_amdgcn_mbcnt_lo((unsigned)m, 0u));
        crow[2 * pos]     = v[t];
        crow[2 * pos + 1] = __int_as_float(jbase + t);
      }
      cbase += (int)__popcll(m);
      if (q[t] == lo) cmask |= (1u << t);
    }
    const int need = KSEL - cbase;
    for (int it = 0; it < need; ++it) {
      float bv = -2.0f; int bj = 0x7fffffff; int bt = 4;
#pragma unroll
      for (int t = 0; t < 4; ++t) {
        if (((cmask >> t) & 1u) && v[t] > bv) { bv = v[t]; bj = jbase + t; bt = t; }
      }
      float rv = bv; int rj = bj;
#pragma unroll
      for (int s = 1; s < 64; s <<= 1) {
        const float ov = __shfl_xor(rv, s);
        const int   oj = __shfl_xor(rj, s);
        if (ov > rv || (ov == rv && oj < rj)) { rv = ov; rj = oj; }
      }
      if (bv == rv && bj == rj) {          // unique winner (j unique)
        crow[2 * (cbase + it)]     = bv;
        crow[2 * (cbase + it) + 1] = __int_as_float(bj);
        cmask &= ~(1u << bt);
      }
    }
  }
  __syncthreads();

  // ---- merge 128 candidates -> exact top-32, softmax; wave w owns 4 rows ----
#pragma unroll
  for (int rr = 0; rr < 4; ++rr) {
    const int r = w * 4 + rr;
    const float4 c4 = *(const float4*)&cand[r][lane * 4];   // 2 pairs per lane
    float v2[2] = { c4.x, c4.z };
    int   j2[2] = { __float_as_int(c4.y), __float_as_int(c4.w) };
    int q2[2];
#pragma unroll
    for (int t = 0; t < 2; ++t) {
      float f = (v2[t] + 1.0f) * 512.0f;
      f = fminf(fmaxf(f, 0.0f), 1023.0f);
      q2[t] = (int)f;
    }
    int lo = 0;
#pragma unroll
    for (int bit = 512; bit >= 1; bit >>= 1) {
      const int mid = lo + bit;
      int cnt = (int)__popcll(__ballot(q2[0] >= mid)) + (int)__popcll(__ballot(q2[1] >= mid));
      if (cnt >= KSEL) lo = mid;
    }
    int cbase = 0;
    unsigned cmask = 0u;
    const int thr = lo + 1;
#pragma unroll
    for (int t = 0; t < 2; ++t) {
      const bool hi = (q2[t] >= thr);
      const unsigned long long m = __ballot(hi);
      if (hi) {
        const int pos = cbase + (int)__builtin_amdgcn_mbcnt_hi(
            (unsigned)(m >> 32), __builtin_amdgcn_mbcnt_lo((unsigned)m, 0u));
        cand[r][2 * pos]     = v2[t];
        cand[r][2 * pos + 1] = __int_as_float(j2[t]);
      }
      cbase += (int)__popcll(m);
      if (q2[t] == lo) cmask |= (1u << t);
    }
    const int need = KSEL - cbase;
    for (int it = 0; it < need; ++it) {
      float bv = -2.0f; int bj = 0x7fffffff; int bt = 2;
#pragma unroll
      for (int t = 0; t < 2; ++t) {
        if (((cmask >> t) & 1u) && v2[t] > bv) { bv = v2[t]; bj = j2[t]; bt = t; }
      }
      float rv = bv; int rj = bj;
#pragma unroll
      for (int s = 1; s < 64; s <<= 1) {
        const float ov = __shfl_xor(rv, s);
        const int   oj = __shfl_xor(rj, s);
        if (ov > rv || (ov == rv && oj < rj)) { rv = ov; rj = oj; }
      }
      if (bv == rv && bj == rj) {
        cand[r][2 * (cbase + it)]     = bv;
        cand[r][2 * (cbase + it) + 1] = __int_as_float(bj);
        cmask &= ~(1u << bt);
      }
    }
    // softmax over the selected 32 (order-invariant); halves duplicate work
    {
      const float x = cand[r][2 * (lane & 31)];
      float mx = x;
#pragma unroll
      for (int s = 16; s >= 1; s >>= 1) mx = fmaxf(mx, __shfl_xor(mx, s));
      const float e = expf(x - mx);
      float sum = e;
#pragma unroll
      for (int s = 16; s >= 1; s >>= 1) sum += __shfl_xor(sum, s);
      if (lane < KSEL) cand[r][2 * lane] = e / sum;
    }
  }
  __syncthreads();

  // write (attn, id) pairs, coalesced float4 (2 pairs per thread)
  {
    const int pidx = tid * 2;            // pair index
    const int r = pidx >> 5, k = pidx & 31;
    const float4 o4 = *(const float4*)&cand[r][2 * k];
    *(float4*)&pairs[((size_t)batch * NPTS + i0 + r) * KSEL + k] = o4;
  }
}

// ================= Kernel B: gather (broadcast-j, conflict-light) ===========
// 512 blocks x 256 threads; 32 rows/block; double-buffered global_load_lds.
__global__ __launch_bounds__(256, 2) void gnn_gather(const float* __restrict__ in,
                                                     const float2* __restrict__ pairs,
                                                     float* __restrict__ out) {
  __shared__ float fst[2][8 * 1028];   // 8 channel-rows per cc pass
  __shared__ float pr[32 * 68];        // [row][34 pairs]: a at 2k, j-bits at 2k+1

  const int p     = blockIdx.x;
  const int batch = ((p & 7) << 1) | ((p >> 3) & 1);
  const int chunk = p >> 4;            // 0..31
  const int i0    = chunk * 32;
  const int tid   = threadIdx.x;
  const int w     = tid >> 6;
  const int lane  = tid & 63;

  const float* __restrict__ fbase = in + (size_t)batch * CT * NPTS;

  // pairs -> LDS (1024 pairs = 512 float4)
  {
    const float4* pb4 = (const float4*)(pairs + ((size_t)batch * NPTS + i0) * KSEL);
#pragma unroll
    for (int h = 0; h < 2; ++h) {
      const int pidx = h * 256 + tid;          // float4 index: 2 pairs each
      const float4 q4 = pb4[pidx];
      const int r = pidx >> 4;                 // 16 float4 per row
      const int u = pidx & 15;
      *(float4*)&pr[r * 68 + u * 4] = q4;
    }
  }

  // stage helper: wave w stages channel-rows {2w, 2w+1} of pass cc into buf
#define STAGE(buf, ccv)                                                          \
  do {                                                                           \
    _Pragma("unroll")                                                            \
    for (int rr = 0; rr < 2; ++rr) {                                             \
      const int crow = w * 2 + rr;                                               \
      const float* src = fbase + (size_t)((ccv) * 8 + crow) * NPTS + lane * 4;   \
      float* dst = &fst[buf][crow * 1028];                                       \
      _Pragma("unroll")                                                          \
      for (int qq = 0; qq < 4; ++qq)                                             \
        __builtin_amdgcn_global_load_lds(                                        \
            (const __attribute__((address_space(1))) void*)(src + qq * 256),     \
            (__attribute__((address_space(3))) void*)(dst + qq * 256), 16, 0, 0);\
    }                                                                            \
  } while (0)

  STAGE(0, 0);
  asm volatile("s_waitcnt vmcnt(0)" ::: "memory");
  __syncthreads();

  const int c   = lane >> 3;           // channel slot 0..7
  const int rl  = lane & 7;
  const int row = w * 8 + rl;          // output row 0..31
  const float* prr = &pr[row * 68];

  for (int cc = 0; cc < 32; ++cc) {
    const int cur = cc & 1;
    if (cc < 31) STAGE(cur ^ 1, cc + 1);

    const float* fb = &fst[cur][c * 1028];
    float o = 0.f;
#pragma unroll
    for (int k = 0; k < KSEL; ++k) {
      const float2 pj = *(const float2*)&prr[2 * k];   // conflict-free broadcast
      o = fmaf(pj.x, fb[__float_as_int(pj.y)], o);     // 8 random j per instr
    }
    out[((size_t)batch * DFEAT + cc * 8 + c) * NPTS + i0 + row] = o;

    asm volatile("s_waitcnt vmcnt(0)" ::: "memory");
    __syncthreads();
  }
#undef STAGE
}

extern "C" void kernel_launch(void* const* d_in, const int* in_sizes, int n_in,
                              void* d_out, int out_size, void* d_ws, size_t ws_size,
                              hipStream_t stream) {
  const float* in = (const float*)d_in[0];
  float* out = (float*)d_out;
  float2* pairs = (float2*)d_ws;       // 16*1024*32*8B = 4 MB
  gnn_sim_topk<<<dim3(1024), dim3(256), 0, stream>>>(in, pairs);
  gnn_gather<<<dim3(512), dim3(256), 0, stream>>>(in, pairs, out);
}

// Round 6
// 119.008 us; speedup vs baseline: 1.1740x; 1.1031x over previous
//
#include <hip/hip_runtime.h>
#include <math.h>

#define CT    320
#define NPTS  1024
#define DFEAT 256
#define DPOS  64
#define KSEL  32

// ================= Kernel A: sim + exact top-32 + softmax -> pairs(ws) ======
// 1024 blocks x 256 threads; 16 rows/block; 4 blocks/CU co-resident.
// Each wave owns 4 FULL rows (all 1024 j, 16 j per lane): top-32 computed
// directly per row from registers -- no partial/merge split, ~6 boundary
// shfl-reduces per wave instead of ~30. rnj for all 1024 points precomputed
// once per block (rows are points of the same batch -> rni = rnjL[i0+r]).
#define AROWS 16
__global__ __launch_bounds__(256, 4) void gnn_sim_topk(const float* __restrict__ in,
                                                       float2* __restrict__ pairs) {
  __shared__ float pi[DPOS * 20];      // [d][i], stride 20 (16B-aligned quads)
  __shared__ float rnjL[NPTS];         // 1/max(norm,eps) per point of this batch
  __shared__ float cand[AROWS][68];    // 32 interleaved (v,j) pairs + pad

  const int p     = blockIdx.x;
  const int batch = ((p & 7) << 1) | ((p >> 3) & 1);   // 2 batches per XCD
  const int chunk = p >> 4;            // 0..63
  const int i0    = chunk * AROWS;
  const int tid   = threadIdx.x;
  const int w     = tid >> 6;
  const int lane  = tid & 63;

  const float* __restrict__ fbase = in + (size_t)batch * CT * NPTS;
  const float* __restrict__ pbase = fbase + (size_t)DFEAT * NPTS;

  // stage raw pos of the 16 rows
  {
    const int i = tid & 15;
    const int d0 = tid >> 4;           // 0..15
#pragma unroll
    for (int pass = 0; pass < 4; ++pass) {
      const int d = pass * 16 + d0;
      pi[d * 20 + i] = pbase[(size_t)d * NPTS + i0 + i];
    }
  }
  // rnj for all 1024 points: thread handles j = tid*4..tid*4+3 (coalesced per d)
  {
    float s0 = 0.f, s1 = 0.f, s2 = 0.f, s3 = 0.f;
    const float* q = pbase + tid * 4;
#pragma unroll 8
    for (int d = 0; d < DPOS; ++d) {
      const float4 v = *(const float4*)(q + (size_t)d * NPTS);
      s0 = fmaf(v.x, v.x, s0);
      s1 = fmaf(v.y, v.y, s1);
      s2 = fmaf(v.z, v.z, s2);
      s3 = fmaf(v.w, v.w, s3);
    }
    float4 r4;
    r4.x = 1.0f / fmaxf(sqrtf(s0), 1e-12f);
    r4.y = 1.0f / fmaxf(sqrtf(s1), 1e-12f);
    r4.z = 1.0f / fmaxf(sqrtf(s2), 1e-12f);
    r4.w = 1.0f / fmaxf(sqrtf(s3), 1e-12f);
    *(float4*)&rnjL[tid * 4] = r4;
  }
  __syncthreads();

  // ---- sim: wave w owns rows w*4..w*4+3; lane owns j = u*256 + lane*4 + t ----
  float acc[4][16];
#pragma unroll
  for (int r = 0; r < 4; ++r)
#pragma unroll
    for (int s = 0; s < 16; ++s) acc[r][s] = 0.f;

  const float* jp = pbase + lane * 4;
#pragma unroll 2
  for (int d = 0; d < DPOS; ++d) {
    const float4 pv4 = *(const float4*)&pi[d * 20 + w * 4];   // broadcast
    const float pr_[4] = {pv4.x, pv4.y, pv4.z, pv4.w};
    float4 jv[4];
#pragma unroll
    for (int u = 0; u < 4; ++u)
      jv[u] = *(const float4*)(jp + (size_t)d * NPTS + u * 256);
#pragma unroll
    for (int r = 0; r < 4; ++r) {
#pragma unroll
      for (int u = 0; u < 4; ++u) {
        acc[r][u*4+0] = fmaf(pr_[r], jv[u].x, acc[r][u*4+0]);
        acc[r][u*4+1] = fmaf(pr_[r], jv[u].y, acc[r][u*4+1]);
        acc[r][u*4+2] = fmaf(pr_[r], jv[u].z, acc[r][u*4+2]);
        acc[r][u*4+3] = fmaf(pr_[r], jv[u].w, acc[r][u*4+3]);
      }
    }
  }

  // per-lane rnj for its 16 j slots
  float4 rv[4];
#pragma unroll
  for (int u = 0; u < 4; ++u) rv[u] = *(const float4*)&rnjL[u * 256 + lane * 4];

  // ---- per-row exact top-32 + softmax, straight from registers ----
#pragma unroll
  for (int r = 0; r < 4; ++r) {
    const int rglob = w * 4 + r;
    const float sc = rnjL[i0 + rglob];         // rni == rnj of the row's point
    float v[16];
#pragma unroll
    for (int u = 0; u < 4; ++u) {
      v[u*4+0] = acc[r][u*4+0] * rv[u].x * sc;
      v[u*4+1] = acc[r][u*4+1] * rv[u].y * sc;
      v[u*4+2] = acc[r][u*4+2] * rv[u].z * sc;
      v[u*4+3] = acc[r][u*4+3] * rv[u].w * sc;
    }
    int q[16];
#pragma unroll
    for (int t = 0; t < 16; ++t) {
      float f = (v[t] + 1.0f) * 512.0f;        // monotone 10-bit quantization
      f = fminf(fmaxf(f, 0.0f), 1023.0f);
      q[t] = (int)f;
    }
    // largest lo with count(q >= lo) >= 32
    int lo = 0;
#pragma unroll
    for (int bit = 512; bit >= 1; bit >>= 1) {
      const int mid = lo + bit;
      int cnt = 0;
#pragma unroll
      for (int t = 0; t < 16; ++t) cnt += (int)__popcll(__ballot(q[t] >= mid));
      if (cnt >= KSEL) lo = mid;
    }
    // compact definite members (q > lo)
    int cbase = 0;
    unsigned cmask = 0u;
    const int thr = lo + 1;
#pragma unroll
    for (int t = 0; t < 16; ++t) {
      const bool hi = (q[t] >= thr);
      const unsigned long long m = __ballot(hi);
      if (hi) {
        const int pos = cbase + (int)__builtin_amdgcn_mbcnt_hi(
            (unsigned)(m >> 32), __builtin_amdgcn_mbcnt_lo((unsigned)m, 0u));
        const int j = (t >> 2) * 256 + lane * 4 + (t & 3);
        *(float2*)&cand[rglob][2 * pos] = make_float2(v[t], __int_as_float(j));
      }
      cbase += (int)__popcll(m);
      if (q[t] == lo) cmask |= (1u << t);
    }
    // boundary bin: exact (v desc, j asc) for remaining slots
    const int need = KSEL - cbase;
    for (int it = 0; it < need; ++it) {
      float bv = -2.0f; int bj = 0x7fffffff; int bt = 16;
#pragma unroll
      for (int t = 0; t < 16; ++t) {
        if (((cmask >> t) & 1u) && v[t] > bv) {
          bv = v[t]; bj = (t >> 2) * 256 + lane * 4 + (t & 3); bt = t;
        }
      }
      float rvv = bv; int rj = bj;
#pragma unroll
      for (int s = 1; s < 64; s <<= 1) {
        const float ov = __shfl_xor(rvv, s);
        const int   oj = __shfl_xor(rj, s);
        if (ov > rvv || (ov == rvv && oj < rj)) { rvv = ov; rj = oj; }
      }
      if (bv == rvv && bj == rj) {             // unique winner (j unique)
        *(float2*)&cand[rglob][2 * (cbase + it)] = make_float2(bv, __int_as_float(bj));
        cmask &= ~(1u << bt);
      }
    }
    // softmax over the selected 32 (order-invariant)
    {
      const float x = cand[rglob][2 * (lane & 31)];
      float mx = x;
#pragma unroll
      for (int s = 16; s >= 1; s >>= 1) mx = fmaxf(mx, __shfl_xor(mx, s));
      const float e = expf(x - mx);
      float sum = e;
#pragma unroll
      for (int s = 16; s >= 1; s >>= 1) sum += __shfl_xor(sum, s);
      if (lane < KSEL) cand[rglob][2 * lane] = e / sum;
    }
  }
  __syncthreads();

  // write (attn, id) pairs, coalesced float4 (2 pairs per thread)
  {
    const int pidx = tid * 2;            // pair index
    const int r = pidx >> 5, k = pidx & 31;
    const float4 o4 = *(const float4*)&cand[r][2 * k];
    *(float4*)&pairs[((size_t)batch * NPTS + i0 + r) * KSEL + k] = o4;
  }
}

// ================= Kernel B: gather (broadcast-j, conflict-light) ===========
// 512 blocks x 256 threads; 32 rows/block; double-buffered global_load_lds.
__global__ __launch_bounds__(256, 2) void gnn_gather(const float* __restrict__ in,
                                                     const float2* __restrict__ pairs,
                                                     float* __restrict__ out) {
  __shared__ float fst[2][8 * 1028];   // 8 channel-rows per cc pass
  __shared__ float pr[32 * 68];        // [row][34 pairs]: a at 2k, j-bits at 2k+1

  const int p     = blockIdx.x;
  const int batch = ((p & 7) << 1) | ((p >> 3) & 1);
  const int chunk = p >> 4;            // 0..31
  const int i0    = chunk * 32;
  const int tid   = threadIdx.x;
  const int w     = tid >> 6;
  const int lane  = tid & 63;

  const float* __restrict__ fbase = in + (size_t)batch * CT * NPTS;

  // pairs -> LDS (1024 pairs = 512 float4)
  {
    const float4* pb4 = (const float4*)(pairs + ((size_t)batch * NPTS + i0) * KSEL);
#pragma unroll
    for (int h = 0; h < 2; ++h) {
      const int pidx = h * 256 + tid;          // float4 index: 2 pairs each
      const float4 q4 = pb4[pidx];
      const int r = pidx >> 4;                 // 16 float4 per row
      const int u = pidx & 15;
      *(float4*)&pr[r * 68 + u * 4] = q4;
    }
  }

  // stage helper: wave w stages channel-rows {2w, 2w+1} of pass cc into buf
#define STAGE(buf, ccv)                                                          \
  do {                                                                           \
    _Pragma("unroll")                                                            \
    for (int rr = 0; rr < 2; ++rr) {                                             \
      const int crow = w * 2 + rr;                                               \
      const float* src = fbase + (size_t)((ccv) * 8 + crow) * NPTS + lane * 4;   \
      float* dst = &fst[buf][crow * 1028];                                       \
      _Pragma("unroll")                                                          \
      for (int qq = 0; qq < 4; ++qq)                                             \
        __builtin_amdgcn_global_load_lds(                                        \
            (const __attribute__((address_space(1))) void*)(src + qq * 256),     \
            (__attribute__((address_space(3))) void*)(dst + qq * 256), 16, 0, 0);\
    }                                                                            \
  } while (0)

  STAGE(0, 0);
  asm volatile("s_waitcnt vmcnt(0)" ::: "memory");
  __syncthreads();

  const int c   = lane >> 3;           // channel slot 0..7
  const int rl  = lane & 7;
  const int row = w * 8 + rl;          // output row 0..31
  const float* prr = &pr[row * 68];

  for (int cc = 0; cc < 32; ++cc) {
    const int cur = cc & 1;
    if (cc < 31) STAGE(cur ^ 1, cc + 1);

    const float* fb = &fst[cur][c * 1028];
    float o = 0.f;
#pragma unroll
    for (int k = 0; k < KSEL; ++k) {
      const float2 pj = *(const float2*)&prr[2 * k];   // conflict-free broadcast
      o = fmaf(pj.x, fb[__float_as_int(pj.y)], o);     // 8 random j per instr
    }
    out[((size_t)batch * DFEAT + cc * 8 + c) * NPTS + i0 + row] = o;

    asm volatile("s_waitcnt vmcnt(0)" ::: "memory");
    __syncthreads();
  }
#undef STAGE
}

extern "C" void kernel_launch(void* const* d_in, const int* in_sizes, int n_in,
                              void* d_out, int out_size, void* d_ws, size_t ws_size,
                              hipStream_t stream) {
  const float* in = (const float*)d_in[0];
  float* out = (float*)d_out;
  float2* pairs = (float2*)d_ws;       // 16*1024*32*8B = 4 MB
  gnn_sim_topk<<<dim3(1024), dim3(256), 0, stream>>>(in, pairs);
  gnn_gather<<<dim3(512), dim3(256), 0, stream>>>(in, pairs, out);
}